// Round 8
// baseline (145.083 us; speedup 1.0000x reference)
//
#include <hip/hip_runtime.h>

typedef __attribute__((ext_vector_type(8))) short bf16x8;
typedef __attribute__((ext_vector_type(4))) float f32x4;
typedef __attribute__((ext_vector_type(4))) float fvec4;
typedef __attribute__((ext_vector_type(4))) int ivec4;

__device__ __forceinline__ unsigned short f2bf(float x) {
    unsigned int u = __float_as_uint(x);
    u += 0x7FFFu + ((u >> 16) & 1u);        // round-to-nearest-even
    return (unsigned short)(u >> 16);
}

// async global->LDS, 16B per lane; LDS dest = wave-uniform base + lane*16.
__device__ __forceinline__ void gl_lds16(const void* g, void* l) {
    __builtin_amdgcn_global_load_lds(
        (__attribute__((address_space(1))) void*)((void*)g),
        (__attribute__((address_space(3))) void*)l, 16, 0, 0);
}

#define SFENCE __builtin_amdgcn_sched_barrier(0)

// ---------------------------------------------------------------------------
// prep: WbT[n][k] = bf16(W[k][n]) via coalesced 32x32 LDS transpose. Grid 64.
// ---------------------------------------------------------------------------
__global__ __launch_bounds__(256) void prep(const float* __restrict__ W,
                                            short* __restrict__ WbT) {
    __shared__ float tile[32][33];
    const int t = threadIdx.x;
    const int bx = blockIdx.x & 7, by = blockIdx.x >> 3;
    const int r0 = by * 32, c0 = bx * 32;
    const int lr = t >> 5, lc = t & 31;
#pragma unroll
    for (int q = 0; q < 4; ++q)
        tile[q * 8 + lr][lc] = W[(r0 + q * 8 + lr) * 256 + c0 + lc];
    __syncthreads();
#pragma unroll
    for (int q = 0; q < 4; ++q)
        WbT[(c0 + q * 8 + lr) * 256 + r0 + lc] = (short)f2bf(tile[lc][q * 8 + lr]);
}

// ---------------------------------------------------------------------------
// setup2: heterogeneous grid 4608. Blocks 0..511 run the wh_f12 role
// (compute-bound: MFMA + LDS); blocks 512..4607 run the bitpack role
// (pure HBM stream, 64 MB read). Read-once streams use nontemporal loads
// to keep L2 clean for the WbT panel reuse and the following fused_agg.
// ---------------------------------------------------------------------------
__global__ __launch_bounds__(256, 4) void setup2(const float* __restrict__ h,
                                                 const short* __restrict__ WbT,
                                                 const float* __restrict__ a,
                                                 const int* __restrict__ adj,
                                                 short* __restrict__ WhT,
                                                 float* __restrict__ f1,
                                                 float* __restrict__ f2,
                                                 unsigned long long* __restrict__ bits) {
    __shared__ short hA[32][264];      // +8 pad -> 2-way bank aliasing (free)
    __shared__ float sp[2][4][32];
    const int t = threadIdx.x;
    const int wid = t >> 6, lane = t & 63;

    if (blockIdx.x >= 512) {
        // ---- bitpack role: wave per row, __ballot per 64 cols; lanes 0..15
        //      store the row's 16 words (128 B contiguous).
        const int row = (blockIdx.x - 512) * 4 + wid;        // 0..16383
        const int* arow = adj + (size_t)row * 1024;
        unsigned long long myword = 0ull;
#pragma unroll
        for (int w = 0; w < 16; ++w) {
            int v = __builtin_nontemporal_load(arow + w * 64 + lane);
            unsigned long long bal = __ballot(v != 0);
            if (lane == w) myword = bal;
        }
        if (lane < 16) bits[(size_t)row * 16 + lane] = myword;
        return;
    }

    // ---- wh_f12 role: 32 nodes/block; WhT bf16-transposed; f1/f2 fused.
    const int quad = lane >> 4, l15 = lane & 15;
    const int m0 = blockIdx.x * 32;

    // stage h-tile (2 rows per 16-thread group; 64 B contiguous/thread)
#pragma unroll
    for (int rr = 0; rr < 2; ++rr) {
        const int r = rr * 16 + (t >> 4), c0 = (t & 15) * 16;
        const float* hp = h + (size_t)(m0 + r) * 256 + c0;
        fvec4 v0 = __builtin_nontemporal_load((const fvec4*)(hp + 0));
        fvec4 v1 = __builtin_nontemporal_load((const fvec4*)(hp + 4));
        fvec4 v2 = __builtin_nontemporal_load((const fvec4*)(hp + 8));
        fvec4 v3 = __builtin_nontemporal_load((const fvec4*)(hp + 12));
        bf16x8 w0, w1;
#pragma unroll
        for (int u = 0; u < 4; ++u) {
            w0[u]     = (short)f2bf(v0[u]);
            w0[u + 4] = (short)f2bf(v1[u]);
            w1[u]     = (short)f2bf(v2[u]);
            w1[u + 4] = (short)f2bf(v3[u]);
        }
        *(bf16x8*)&hA[r][c0] = w0;
        *(bf16x8*)&hA[r][c0 + 8] = w1;
    }
    __syncthreads();

    f32x4 acc[2][4] = {};
#pragma unroll
    for (int kt = 0; kt < 8; ++kt) {
        const int k0 = kt * 32;
        bf16x8 bv[4];
#pragma unroll
        for (int ft = 0; ft < 4; ++ft)
            bv[ft] = *(const bf16x8*)(WbT + (size_t)(wid * 64 + ft * 16 + l15) * 256 + k0 + quad * 8);
        bf16x8 a0 = *(const bf16x8*)&hA[l15][k0 + quad * 8];
        bf16x8 a1 = *(const bf16x8*)&hA[16 + l15][k0 + quad * 8];
#pragma unroll
        for (int ft = 0; ft < 4; ++ft) {
            acc[0][ft] = __builtin_amdgcn_mfma_f32_16x16x32_bf16(a0, bv[ft], acc[0][ft], 0, 0, 0);
            acc[1][ft] = __builtin_amdgcn_mfma_f32_16x16x32_bf16(a1, bv[ft], acc[1][ft], 0, 0, 0);
        }
    }

    // WhT store (C row = quad*4+reg, col f = wid*64+ft*16+l15)
    const int b = m0 >> 10;
#pragma unroll
    for (int mf = 0; mf < 2; ++mf) {
        const int il0 = (m0 & 1023) + mf * 16 + quad * 4;
#pragma unroll
        for (int ft = 0; ft < 4; ++ft) {
            const int f = wid * 64 + ft * 16 + l15;
            ushort4 pk;
            pk.x = f2bf(acc[mf][ft][0]);
            pk.y = f2bf(acc[mf][ft][1]);
            pk.z = f2bf(acc[mf][ft][2]);
            pk.w = f2bf(acc[mf][ft][3]);
            *(ushort4*)(WhT + ((size_t)b << 18) + (size_t)f * 1024 + il0) = pk;
        }
    }

    // f1/f2 from fp32 acc: dot with a1/a2 over this wave's 64-f slice
    float a1v[4], a2v[4];
#pragma unroll
    for (int ft = 0; ft < 4; ++ft) {
        a1v[ft] = a[wid * 64 + ft * 16 + l15];
        a2v[ft] = a[256 + wid * 64 + ft * 16 + l15];
    }
    float p1[2][4] = {}, p2[2][4] = {};
#pragma unroll
    for (int mf = 0; mf < 2; ++mf)
#pragma unroll
        for (int ft = 0; ft < 4; ++ft)
#pragma unroll
            for (int r = 0; r < 4; ++r) {
                p1[mf][r] += acc[mf][ft][r] * a1v[ft];
                p2[mf][r] += acc[mf][ft][r] * a2v[ft];
            }
#pragma unroll
    for (int off = 1; off < 16; off <<= 1)
#pragma unroll
        for (int mf = 0; mf < 2; ++mf)
#pragma unroll
            for (int r = 0; r < 4; ++r) {
                p1[mf][r] += __shfl_xor(p1[mf][r], off);
                p2[mf][r] += __shfl_xor(p2[mf][r], off);
            }
    if (l15 == 0)
#pragma unroll
        for (int mf = 0; mf < 2; ++mf)
#pragma unroll
            for (int r = 0; r < 4; ++r) {
                sp[0][wid][mf * 16 + quad * 4 + r] = p1[mf][r];
                sp[1][wid][mf * 16 + quad * 4 + r] = p2[mf][r];
            }
    __syncthreads();
    if (t < 32) {
        f1[m0 + t] = sp[0][0][t] + sp[0][1][t] + sp[0][2][t] + sp[0][3][t];
        f2[m0 + t] = sp[1][0][t] + sp[1][1][t] + sp[1][2][t] + sp[1][3][t];
    }
}

// ---------------------------------------------------------------------------
// fused_agg v8 (occupancy experiment): BN=128 halves -> grid 512 blocks,
// 2 blocks/CU (4 waves/SIMD) so cross-block slip hides the per-tile
// barrier/latency bubbles that 1 block/CU exposed. Same counted-vmcnt ring:
// BM=64, BK=64, 3-deep Bs ring of 16 KB tiles, vmcnt(2) (never 0 mid-loop).
// 8 waves = 2M x 4N, wave tile 32m x 32n (dup-optimal: 64 KB LDS-read/tile).
// P (64x64) generated per block (chip-wide pgen x2 -- cheap VALU). LDS
// ~76 KB/block: Bs 48K + Ps 16K + bits 8K + f2 4K; lred/linv alias dead Ps.
// ---------------------------------------------------------------------------
__global__ __launch_bounds__(512, 4) void fused_agg(const unsigned long long* __restrict__ bitsG,
                                                    const float* __restrict__ f1g,
                                                    const float* __restrict__ f2g,
                                                    const short* __restrict__ WhT,
                                                    float* __restrict__ out) {
    __shared__ __align__(16) short Bs[3][128 * 64];  // 48 KB ring, swizzled rows
    __shared__ __align__(16) short Ps[2][64 * 64];   // 16 KB dbuf, swizzled rows
    __shared__ unsigned long long bitsS[16 * 64];    // 8 KB, [word][row]
    __shared__ float f2s[1024];                      // 4 KB

    const int t = threadIdx.x;
    const int wid = t >> 6, lane = t & 63;
    const int quad = lane >> 4, l15 = lane & 15;

    // decode: xcd = id&7, b = xcd + 8*(rest&1), r2 = rest>>1: n-half, m-tile
    const int id = blockIdx.x;
    const int xcd = id & 7, rest = id >> 3;
    const int b = xcd + 8 * (rest & 1);
    const int r2 = rest >> 1;
    const int n0 = (r2 & 1) * 128;
    const int m0 = (r2 >> 1) * 64;

    const short* Wb = WhT + ((size_t)b << 18);

    // ---- prologue: bits (transposed [word][row]) + f2 + f1 resident
    {
        const unsigned long long* bsrc = bitsG + (size_t)((b << 10) + m0) * 16;
        ulonglong2 bv = ((const ulonglong2*)bsrc)[t];     // words 2t, 2t+1
        const int g0 = 2 * t, g1 = 2 * t + 1;
        bitsS[(g0 & 15) * 64 + (g0 >> 4)] = bv.x;
        bitsS[(g1 & 15) * 64 + (g1 >> 4)] = bv.y;
        ((float2*)f2s)[t] = ((const float2*)(f2g + (b << 10)))[t];
    }
    const int pr = t >> 3, ps = t & 7;            // P-gen role: row, chunk
    const float f1r = f1g[(b << 10) + m0 + pr];
    __syncthreads();                              // drains all prologue vmem

    // ---- staging: chunk c = t + 512q -> LDS byte c*16 (linear per wave);
    //      global slot = (c&7) ^ (row&7), row = c>>3 (read-side involution)
    auto stage = [&](int T, short* buf) {
#pragma unroll
        for (int q = 0; q < 2; ++q) {
            const int c = t + 512 * q;
            const int rr = c >> 3;                 // 0..127
            const int sl = (c & 7) ^ (rr & 7);
            gl_lds16(Wb + (size_t)(n0 + rr) * 1024 + T * 64 + sl * 8, buf + c * 8);
        }
    };

    float lacc = 0.f;
    auto pgen = [&](int T, short* pbuf) {
        unsigned int m8 = (unsigned int)(bitsS[T * 64 + pr] >> (ps * 8)) & 0xffu;
        float4 fa = *(const float4*)(f2s + T * 64 + ps * 8);
        float4 fb = *(const float4*)(f2s + T * 64 + ps * 8 + 4);
        float xv[8] = {fa.x, fa.y, fa.z, fa.w, fb.x, fb.y, fb.z, fb.w};
        bf16x8 pw;
#pragma unroll
        for (int u = 0; u < 8; ++u) {
            float x = f1r + xv[u];
            x = fmaxf(x, 0.2f * x);                       // leaky relu
            float pv = ((m8 >> u) & 1u) ? __expf(x) : 0.f; // unnorm, m=0 (e<=~6.5)
            lacc += pv;
            pw[u] = (short)f2bf(pv);
        }
        *(bf16x8*)(pbuf + pr * 64 + ((ps ^ (pr & 7)) * 8)) = pw;
    };

    const int wm = wid >> 2, wn = wid & 3;
    const int mh = wm * 32, nq = wn * 32;
    f32x4 acc[2][2] = {};

    auto step = [&](const short* pbuf, const short* bbuf) {
#pragma unroll
        for (int kt = 0; kt < 2; ++kt) {
            const int w = kt * 4 + quad;
            bf16x8 av[2], bv[2];
#pragma unroll
            for (int mf = 0; mf < 2; ++mf) {
                const int ra = mh + mf * 16 + l15;
                av[mf] = *(const bf16x8*)(pbuf + ra * 64 + ((w ^ (ra & 7)) * 8));
            }
#pragma unroll
            for (int nf = 0; nf < 2; ++nf) {
                const int rb = nq + nf * 16 + l15;
                bv[nf] = *(const bf16x8*)(bbuf + rb * 64 + ((w ^ (rb & 7)) * 8));
            }
#pragma unroll
            for (int mf = 0; mf < 2; ++mf)
#pragma unroll
                for (int nf = 0; nf < 2; ++nf)
                    acc[mf][nf] = __builtin_amdgcn_mfma_f32_16x16x32_bf16(av[mf], bv[nf], acc[mf][nf], 0, 0, 0);
        }
    };

    // ---- pipeline prologue: tiles 0,1 in flight; P(0) built
    stage(0, Bs[0]);
    stage(1, Bs[1]);
    pgen(0, Ps[0]);
    asm volatile("s_waitcnt lgkmcnt(0)" ::: "memory");
    SFENCE;
    asm volatile("s_waitcnt vmcnt(2)" ::: "memory");   // tile 0 landed, 1 in flight
    SFENCE;
    __builtin_amdgcn_s_barrier();
    SFENCE;

    // ---- main loop: 16 k-tiles, ONE barrier per tile, counted vmcnt
#pragma unroll
    for (int T = 0; T < 16; ++T) {
        if (T < 14) stage(T + 2, Bs[(T + 2) % 3]);     // overwrites Bs[(T-1)%3]
        if (T < 15) pgen(T + 1, Ps[(T + 1) & 1]);      // overwrites Ps[(T-1)&1]
        __builtin_amdgcn_s_setprio(1);
        step(Ps[T & 1], Bs[T % 3]);
        __builtin_amdgcn_s_setprio(0);
        asm volatile("s_waitcnt lgkmcnt(0)" ::: "memory");  // P(T+1) writes drained
        SFENCE;
        if (T < 14) {
            asm volatile("s_waitcnt vmcnt(2)" ::: "memory");  // tile T+1 landed (own wave)
        } else if (T == 14) {
            asm volatile("s_waitcnt vmcnt(0)" ::: "memory");  // tile 15: pipeline drain
        }
        SFENCE;
        __builtin_amdgcn_s_barrier();   // cross-wave: tile T+1 + P(T+1) visible;
        SFENCE;                         // all reads of Bs[T%3]/Ps[T&1] complete
    }

    // ---- row-sum reduce: lred/linv alias the now-dead Ps (Ps[0] last read T=14)
    float* lred = (float*)&Ps[0][0];
    float* linv = lred + 512;
    lred[t] = lacc;
    __syncthreads();
    if (t < 64) {
        const float* lp = lred + t * 8;
        linv[t] = 1.0f / (((lp[0] + lp[1]) + (lp[2] + lp[3])) +
                          ((lp[4] + lp[5]) + (lp[6] + lp[7])));
    }
    __syncthreads();

    // ---- epilogue: C row = mh + mf*16 + quad*4 + reg, col = n0+nq+nf*16+l15
#pragma unroll
    for (int mf = 0; mf < 2; ++mf) {
        const int il = mh + mf * 16 + quad * 4;
        const float i0 = linv[il], i1 = linv[il + 1];
        const float i2 = linv[il + 2], i3 = linv[il + 3];
#pragma unroll
        for (int nf = 0; nf < 2; ++nf) {
            float* op = out + (size_t)((b << 10) + m0 + il) * 256 + n0 + nq + nf * 16 + l15;
            op[0]   = acc[mf][nf][0] * i0;
            op[256] = acc[mf][nf][1] * i1;
            op[512] = acc[mf][nf][2] * i2;
            op[768] = acc[mf][nf][3] * i3;
        }
    }
}

// ---------------------------------------------------------------------------
extern "C" void kernel_launch(void* const* d_in, const int* in_sizes, int n_in,
                              void* d_out, int out_size, void* d_ws, size_t ws_size,
                              hipStream_t stream) {
    const float* h   = (const float*)d_in[0];
    const int*   adj = (const int*)d_in[1];
    const float* W   = (const float*)d_in[2];
    const float* a   = (const float*)d_in[3];
    float* out = (float*)d_out;

    short* WbT = (short*)d_ws;                       // 128 KB
    float* f1  = (float*)(WbT + 65536);              // 64 KB
    float* f2  = f1 + 16384;                         // 64 KB
    short* WhT = (short*)(f2 + 16384);               // 8 MB
    unsigned long long* bits =
        (unsigned long long*)(WhT + 16 * 256 * 1024);// 2 MB

    prep<<<64, 256, 0, stream>>>(W, WbT);
    setup2<<<4608, 256, 0, stream>>>(h, WbT, a, adj, WhT, f1, f2, bits);
    fused_agg<<<512, 512, 0, stream>>>(bits, f1, f2, WhT, out);
}

// Round 9
// 142.813 us; speedup vs baseline: 1.0159x; 1.0159x over previous
//
#include <hip/hip_runtime.h>

typedef __attribute__((ext_vector_type(8))) short bf16x8;
typedef __attribute__((ext_vector_type(4))) float f32x4;
typedef __attribute__((ext_vector_type(4))) float fvec4;

__device__ __forceinline__ unsigned short f2bf(float x) {
    unsigned int u = __float_as_uint(x);
    u += 0x7FFFu + ((u >> 16) & 1u);        // round-to-nearest-even
    return (unsigned short)(u >> 16);
}

// async global->LDS, 16B per lane; LDS dest = wave-uniform base + lane*16.
__device__ __forceinline__ void gl_lds16(const void* g, void* l) {
    __builtin_amdgcn_global_load_lds(
        (__attribute__((address_space(1))) void*)((void*)g),
        (__attribute__((address_space(3))) void*)l, 16, 0, 0);
}

#define SFENCE __builtin_amdgcn_sched_barrier(0)

// ---------------------------------------------------------------------------
// prep: WbT[n][k] = bf16(W[k][n]) via coalesced 32x32 LDS transpose. Grid 64.
// ---------------------------------------------------------------------------
__global__ __launch_bounds__(256) void prep(const float* __restrict__ W,
                                            short* __restrict__ WbT) {
    __shared__ float tile[32][33];
    const int t = threadIdx.x;
    const int bx = blockIdx.x & 7, by = blockIdx.x >> 3;
    const int r0 = by * 32, c0 = bx * 32;
    const int lr = t >> 5, lc = t & 31;
#pragma unroll
    for (int q = 0; q < 4; ++q)
        tile[q * 8 + lr][lc] = W[(r0 + q * 8 + lr) * 256 + c0 + lc];
    __syncthreads();
#pragma unroll
    for (int q = 0; q < 4; ++q)
        WbT[(c0 + q * 8 + lr) * 256 + r0 + lc] = (short)f2bf(tile[lc][q * 8 + lr]);
}

// ---------------------------------------------------------------------------
// setup2: heterogeneous grid 4608. Blocks 0..511 run the wh_f12 role
// (compute-bound); blocks 512..4607 run the bitpack role (pure HBM stream).
// WhT is stored TILE-MAJOR: WhT[b][T][f][64], T = j>>6 -- each (b,T) tile is
// a dense 32 KB block so fused_agg's staging reads are fully contiguous
// (round-8 diagnosis: the old f-major layout forced 2 KB-strided tile reads,
// which alias onto few L2 channels and cap effective L2 BW at ~5-6 TB/s).
// ---------------------------------------------------------------------------
__global__ __launch_bounds__(256, 4) void setup2(const float* __restrict__ h,
                                                 const short* __restrict__ WbT,
                                                 const float* __restrict__ a,
                                                 const int* __restrict__ adj,
                                                 short* __restrict__ WhT,
                                                 float* __restrict__ f1,
                                                 float* __restrict__ f2,
                                                 unsigned long long* __restrict__ bits) {
    __shared__ short hA[32][264];      // +8 pad -> 2-way bank aliasing (free)
    __shared__ float sp[2][4][32];
    const int t = threadIdx.x;
    const int wid = t >> 6, lane = t & 63;

    if (blockIdx.x >= 512) {
        // ---- bitpack role: wave per row, __ballot per 64 cols; lanes 0..15
        //      store the row's 16 words (128 B contiguous).
        const int row = (blockIdx.x - 512) * 4 + wid;        // 0..16383
        const int* arow = adj + (size_t)row * 1024;
        unsigned long long myword = 0ull;
#pragma unroll
        for (int w = 0; w < 16; ++w) {
            int v = __builtin_nontemporal_load(arow + w * 64 + lane);
            unsigned long long bal = __ballot(v != 0);
            if (lane == w) myword = bal;
        }
        if (lane < 16) bits[(size_t)row * 16 + lane] = myword;
        return;
    }

    // ---- wh_f12 role: 32 nodes/block; WhT bf16 tile-major; f1/f2 fused.
    const int quad = lane >> 4, l15 = lane & 15;
    const int m0 = blockIdx.x * 32;

    // stage h-tile (2 rows per 16-thread group; 64 B contiguous/thread)
#pragma unroll
    for (int rr = 0; rr < 2; ++rr) {
        const int r = rr * 16 + (t >> 4), c0 = (t & 15) * 16;
        const float* hp = h + (size_t)(m0 + r) * 256 + c0;
        fvec4 v0 = __builtin_nontemporal_load((const fvec4*)(hp + 0));
        fvec4 v1 = __builtin_nontemporal_load((const fvec4*)(hp + 4));
        fvec4 v2 = __builtin_nontemporal_load((const fvec4*)(hp + 8));
        fvec4 v3 = __builtin_nontemporal_load((const fvec4*)(hp + 12));
        bf16x8 w0, w1;
#pragma unroll
        for (int u = 0; u < 4; ++u) {
            w0[u]     = (short)f2bf(v0[u]);
            w0[u + 4] = (short)f2bf(v1[u]);
            w1[u]     = (short)f2bf(v2[u]);
            w1[u + 4] = (short)f2bf(v3[u]);
        }
        *(bf16x8*)&hA[r][c0] = w0;
        *(bf16x8*)&hA[r][c0 + 8] = w1;
    }
    __syncthreads();

    f32x4 acc[2][4] = {};
#pragma unroll
    for (int kt = 0; kt < 8; ++kt) {
        const int k0 = kt * 32;
        bf16x8 bv[4];
#pragma unroll
        for (int ft = 0; ft < 4; ++ft)
            bv[ft] = *(const bf16x8*)(WbT + (size_t)(wid * 64 + ft * 16 + l15) * 256 + k0 + quad * 8);
        bf16x8 a0 = *(const bf16x8*)&hA[l15][k0 + quad * 8];
        bf16x8 a1 = *(const bf16x8*)&hA[16 + l15][k0 + quad * 8];
#pragma unroll
        for (int ft = 0; ft < 4; ++ft) {
            acc[0][ft] = __builtin_amdgcn_mfma_f32_16x16x32_bf16(a0, bv[ft], acc[0][ft], 0, 0, 0);
            acc[1][ft] = __builtin_amdgcn_mfma_f32_16x16x32_bf16(a1, bv[ft], acc[1][ft], 0, 0, 0);
        }
    }

    // WhT store, tile-major: addr = (b<<18) + (j>>6)*16384 + f*64 + (j&63)
    const int b = m0 >> 10;
#pragma unroll
    for (int mf = 0; mf < 2; ++mf) {
        const int il0 = (m0 & 1023) + mf * 16 + quad * 4;   // j index (mult of 4)
        const int T = il0 >> 6, jw = il0 & 63;
#pragma unroll
        for (int ft = 0; ft < 4; ++ft) {
            const int f = wid * 64 + ft * 16 + l15;
            ushort4 pk;
            pk.x = f2bf(acc[mf][ft][0]);
            pk.y = f2bf(acc[mf][ft][1]);
            pk.z = f2bf(acc[mf][ft][2]);
            pk.w = f2bf(acc[mf][ft][3]);
            *(ushort4*)(WhT + ((size_t)b << 18) + T * 16384 + (size_t)f * 64 + jw) = pk;
        }
    }

    // f1/f2 from fp32 acc: dot with a1/a2 over this wave's 64-f slice
    float a1v[4], a2v[4];
#pragma unroll
    for (int ft = 0; ft < 4; ++ft) {
        a1v[ft] = a[wid * 64 + ft * 16 + l15];
        a2v[ft] = a[256 + wid * 64 + ft * 16 + l15];
    }
    float p1[2][4] = {}, p2[2][4] = {};
#pragma unroll
    for (int mf = 0; mf < 2; ++mf)
#pragma unroll
        for (int ft = 0; ft < 4; ++ft)
#pragma unroll
            for (int r = 0; r < 4; ++r) {
                p1[mf][r] += acc[mf][ft][r] * a1v[ft];
                p2[mf][r] += acc[mf][ft][r] * a2v[ft];
            }
#pragma unroll
    for (int off = 1; off < 16; off <<= 1)
#pragma unroll
        for (int mf = 0; mf < 2; ++mf)
#pragma unroll
            for (int r = 0; r < 4; ++r) {
                p1[mf][r] += __shfl_xor(p1[mf][r], off);
                p2[mf][r] += __shfl_xor(p2[mf][r], off);
            }
    if (l15 == 0)
#pragma unroll
        for (int mf = 0; mf < 2; ++mf)
#pragma unroll
            for (int r = 0; r < 4; ++r) {
                sp[0][wid][mf * 16 + quad * 4 + r] = p1[mf][r];
                sp[1][wid][mf * 16 + quad * 4 + r] = p2[mf][r];
            }
    __syncthreads();
    if (t < 32) {
        f1[m0 + t] = sp[0][0][t] + sp[0][1][t] + sp[0][2][t] + sp[0][3][t];
        f2[m0 + t] = sp[1][0][t] + sp[1][1][t] + sp[1][2][t] + sp[1][3][t];
    }
}

// ---------------------------------------------------------------------------
// fused_agg v9: v7 structure (best measured) + tile-major B staging.
// BM=64, BN=256, BK=64, grid 256 (1 block/CU), 512 thr = 8 waves (2M x 4N),
// wave tile 32m x 64n. Counted-vmcnt 3-deep ring, ONE s_barrier per k-tile,
// setprio around MFMA. stage(T) now reads ONE CONTIGUOUS 32 KB block
// (tile-major WhT) -- full L2 lines, no 2 KB-stride channel aliasing.
// ---------------------------------------------------------------------------
__global__ __launch_bounds__(512, 2) void fused_agg(const unsigned long long* __restrict__ bitsG,
                                                    const float* __restrict__ f1g,
                                                    const float* __restrict__ f2g,
                                                    const short* __restrict__ WhT,
                                                    float* __restrict__ out) {
    __shared__ short Bs[3][256 * 64];             // 96 KB ring, swizzled rows
    __shared__ short Ps[2][64 * 64];              // 16 KB dbuf, swizzled rows
    __shared__ unsigned long long bitsS[16 * 64]; // 8 KB, [word][row] (transposed)
    __shared__ float f2s[1024];                   // 4 KB
    __shared__ float lred[512];
    __shared__ float linv[64];

    const int t = threadIdx.x;
    const int wid = t >> 6, lane = t & 63;
    const int quad = lane >> 4, l15 = lane & 15;

    // XCD-aware decode: xcd = id&7, b = xcd + 8*(rest&1), m-tile = rest>>1
    const int id = blockIdx.x;
    const int xcd = id & 7, rest = id >> 3;
    const int b = xcd + 8 * (rest & 1);
    const int m0 = (rest >> 1) * 64;

    const short* Wb = WhT + ((size_t)b << 18);

    // ---- prologue: bits (transposed [word][row]) + f2 + f1 resident
    {
        const unsigned long long* bsrc = bitsG + (size_t)((b << 10) + m0) * 16;
        ulonglong2 bv = ((const ulonglong2*)bsrc)[t];     // words 2t, 2t+1
        const int g0 = 2 * t, g1 = 2 * t + 1;
        bitsS[(g0 & 15) * 64 + (g0 >> 4)] = bv.x;
        bitsS[(g1 & 15) * 64 + (g1 >> 4)] = bv.y;
        ((float2*)f2s)[t] = ((const float2*)(f2g + (b << 10)))[t];
    }
    const int pr = t >> 3, ps = t & 7;            // P-gen role: row, chunk
    const float f1r = f1g[(b << 10) + m0 + pr];
    __syncthreads();                              // drains all prologue vmem

    // ---- staging: tile-major source -- chunk c reads within ONE contiguous
    //      32 KB tile; slot permuted within each 128 B line (read involution).
    auto stage = [&](int T, short* buf) {
        const short* src = Wb + T * 16384;
#pragma unroll
        for (int q = 0; q < 4; ++q) {
            const int c = t + 512 * q;
            const int rr = c >> 3;                 // row 0..255
            const int sl = (c & 7) ^ (rr & 7);     // permuted 16 B slot in line
            gl_lds16(src + rr * 64 + sl * 8, buf + c * 8);
        }
    };

    float lacc = 0.f;
    auto pgen = [&](int T, short* pbuf) {
        unsigned int m8 = (unsigned int)(bitsS[T * 64 + pr] >> (ps * 8)) & 0xffu;
        float4 fa = *(const float4*)(f2s + T * 64 + ps * 8);
        float4 fb = *(const float4*)(f2s + T * 64 + ps * 8 + 4);
        float xv[8] = {fa.x, fa.y, fa.z, fa.w, fb.x, fb.y, fb.z, fb.w};
        bf16x8 pw;
#pragma unroll
        for (int u = 0; u < 8; ++u) {
            float x = f1r + xv[u];
            x = fmaxf(x, 0.2f * x);                       // leaky relu
            float pv = ((m8 >> u) & 1u) ? __expf(x) : 0.f; // unnorm, m=0 (e<=~6.5)
            lacc += pv;
            pw[u] = (short)f2bf(pv);
        }
        *(bf16x8*)(pbuf + pr * 64 + ((ps ^ (pr & 7)) * 8)) = pw;
    };

    const int wm = wid >> 2, wn = wid & 3;
    const int mh = wm * 32, nq = wn * 64;
    f32x4 acc[2][4] = {};

    auto step = [&](const short* pbuf, const short* bbuf) {
#pragma unroll
        for (int kt = 0; kt < 2; ++kt) {
            const int w = kt * 4 + quad;
            bf16x8 av[2], bv[4];
#pragma unroll
            for (int mf = 0; mf < 2; ++mf) {
                const int ra = mh + mf * 16 + l15;
                av[mf] = *(const bf16x8*)(pbuf + ra * 64 + ((w ^ (ra & 7)) * 8));
            }
#pragma unroll
            for (int nf = 0; nf < 4; ++nf) {
                const int rb = nq + nf * 16 + l15;
                bv[nf] = *(const bf16x8*)(bbuf + rb * 64 + ((w ^ (rb & 7)) * 8));
            }
#pragma unroll
            for (int mf = 0; mf < 2; ++mf)
#pragma unroll
                for (int nf = 0; nf < 4; ++nf)
                    acc[mf][nf] = __builtin_amdgcn_mfma_f32_16x16x32_bf16(av[mf], bv[nf], acc[mf][nf], 0, 0, 0);
        }
    };

    // ---- pipeline prologue: tiles 0,1 in flight; P(0) built
    stage(0, Bs[0]);
    stage(1, Bs[1]);
    pgen(0, Ps[0]);
    asm volatile("s_waitcnt lgkmcnt(0)" ::: "memory");
    SFENCE;
    asm volatile("s_waitcnt vmcnt(4)" ::: "memory");   // tile 0 landed, 1 in flight
    SFENCE;
    __builtin_amdgcn_s_barrier();
    SFENCE;

    // ---- main loop: 16 k-tiles, ONE barrier per tile, counted vmcnt
#pragma unroll
    for (int T = 0; T < 16; ++T) {
        if (T < 14) stage(T + 2, Bs[(T + 2) % 3]);     // overwrites Bs[(T-1)%3]
        if (T < 15) pgen(T + 1, Ps[(T + 1) & 1]);      // overwrites Ps[(T-1)&1]
        __builtin_amdgcn_s_setprio(1);
        step(Ps[T & 1], Bs[T % 3]);
        __builtin_amdgcn_s_setprio(0);
        asm volatile("s_waitcnt lgkmcnt(0)" ::: "memory");  // P(T+1) writes drained
        SFENCE;
        if (T < 14) {
            asm volatile("s_waitcnt vmcnt(4)" ::: "memory");  // tile T+1 landed (own wave)
        } else if (T == 14) {
            asm volatile("s_waitcnt vmcnt(0)" ::: "memory");  // tile 15: pipeline drain
        }
        SFENCE;
        __builtin_amdgcn_s_barrier();   // cross-wave: tile T+1 + P(T+1) visible;
        SFENCE;                         // all reads of Bs[T%3]/Ps[T&1] complete
    }

    // ---- row-sum reduce: 8 partials per row (lred[r*8+sub]) -> 1/l
    lred[t] = lacc;
    __syncthreads();
    if (t < 64) {
        const float* lp = lred + t * 8;
        linv[t] = 1.0f / (((lp[0] + lp[1]) + (lp[2] + lp[3])) +
                          ((lp[4] + lp[5]) + (lp[6] + lp[7])));
    }
    __syncthreads();

    // ---- epilogue: C row = mh + mf*16 + quad*4 + reg, col = nq + nf*16 + l15
#pragma unroll
    for (int mf = 0; mf < 2; ++mf) {
        const int il = mh + mf * 16 + quad * 4;
        const float i0 = linv[il], i1 = linv[il + 1];
        const float i2 = linv[il + 2], i3 = linv[il + 3];
#pragma unroll
        for (int nf = 0; nf < 4; ++nf) {
            float* op = out + (size_t)((b << 10) + m0 + il) * 256 + nq + nf * 16 + l15;
            op[0]   = acc[mf][nf][0] * i0;
            op[256] = acc[mf][nf][1] * i1;
            op[512] = acc[mf][nf][2] * i2;
            op[768] = acc[mf][nf][3] * i3;
        }
    }
}

// ---------------------------------------------------------------------------
extern "C" void kernel_launch(void* const* d_in, const int* in_sizes, int n_in,
                              void* d_out, int out_size, void* d_ws, size_t ws_size,
                              hipStream_t stream) {
    const float* h   = (const float*)d_in[0];
    const int*   adj = (const int*)d_in[1];
    const float* W   = (const float*)d_in[2];
    const float* a   = (const float*)d_in[3];
    float* out = (float*)d_out;

    short* WbT = (short*)d_ws;                       // 128 KB
    float* f1  = (float*)(WbT + 65536);              // 64 KB
    float* f2  = f1 + 16384;                         // 64 KB
    short* WhT = (short*)(f2 + 16384);               // 8 MB (tile-major)
    unsigned long long* bits =
        (unsigned long long*)(WhT + 16 * 256 * 1024);// 2 MB

    prep<<<64, 256, 0, stream>>>(W, WbT);
    setup2<<<4608, 256, 0, stream>>>(h, WbT, a, adj, WhT, f1, f2, bits);
    fused_agg<<<256, 512, 0, stream>>>(bits, f1, f2, WhT, out);
}